// Round 2
// baseline (556.672 us; speedup 1.0000x reference)
//
#include <hip/hip_runtime.h>
#include <hip/hip_bf16.h>
#include <stdint.h>

static constexpr int NN = 50000;   // nodes
static constexpr int NE = 400000;  // edges

// ---------------- CSR build ----------------
// NOTE: harness pushes integer inputs as int32 — edge_index is const int*.

__global__ void k_count(const int* __restrict__ ei, unsigned* __restrict__ cnt) {
    int e = blockIdx.x * blockDim.x + threadIdx.x;
    if (e < NE) atomicAdd(&cnt[ei[NE + e]], 1u);
}

__global__ void k_dinv(const unsigned* __restrict__ cnt, float* __restrict__ dinv,
                       float* __restrict__ selfw) {
    int i = blockIdx.x * blockDim.x + threadIdx.x;
    if (i < NN) {
        float deg = (float)(cnt[i] + 1u);  // in-degree + self-loop
        dinv[i] = rsqrtf(deg);
        selfw[i] = 1.0f / deg;             // dinv^2 for the self-loop edge
    }
}

// Exclusive scan of cnt[0..NN) -> offs[0..NN], single block of 1024.
__global__ __launch_bounds__(1024) void k_scan(const unsigned* __restrict__ cnt,
                                               unsigned* __restrict__ offs) {
    __shared__ unsigned sh[1024];
    __shared__ unsigned carry;
    if (threadIdx.x == 0) carry = 0u;
    __syncthreads();
    for (int base = 0; base < NN; base += 1024) {
        int i = base + (int)threadIdx.x;
        unsigned v = (i < NN) ? cnt[i] : 0u;
        sh[threadIdx.x] = v;
        __syncthreads();
        #pragma unroll
        for (int off = 1; off < 1024; off <<= 1) {
            unsigned add = (threadIdx.x >= (unsigned)off) ? sh[threadIdx.x - off] : 0u;
            __syncthreads();
            sh[threadIdx.x] += add;
            __syncthreads();
        }
        if (i < NN) offs[i] = carry + sh[threadIdx.x] - v;  // exclusive
        __syncthreads();
        if (threadIdx.x == 1023) carry += sh[1023];
        __syncthreads();
    }
    if (threadIdx.x == 0) offs[NN] = carry;
}

__global__ void k_fill(const int* __restrict__ ei, const unsigned* __restrict__ offs,
                       unsigned* __restrict__ cursor, const float* __restrict__ dinv,
                       unsigned* __restrict__ csr_src, float* __restrict__ csr_w) {
    int e = blockIdx.x * blockDim.x + threadIdx.x;
    if (e < NE) {
        int s = ei[e];
        int d = ei[NE + e];
        unsigned pos = offs[d] + atomicAdd(&cursor[d], 1u);
        csr_src[pos] = (unsigned)s;
        csr_w[pos] = dinv[s] * dinv[d];
    }
}

// ---------------- Aggregation: y = A_hat * x  (one wave per node) ----------------

template <int VEC>  // floats per lane; F = 64*VEC (VEC=2 -> F=128, VEC=4 -> F=256)
__global__ __launch_bounds__(256) void k_aggregate(
        const float* __restrict__ x, float* __restrict__ y,
        const unsigned* __restrict__ offs, const unsigned* __restrict__ csr_src,
        const float* __restrict__ csr_w, const float* __restrict__ selfw) {
    const int F = 64 * VEC;
    int node = blockIdx.x * 4 + ((int)threadIdx.x >> 6);
    int lane = (int)threadIdx.x & 63;
    if (node >= NN) return;

    float acc[VEC];
    const float* xs = x + (size_t)node * F + lane * VEC;
    float sw = selfw[node];
    if constexpr (VEC == 2) {
        float2 v = *reinterpret_cast<const float2*>(xs);
        acc[0] = sw * v.x; acc[1] = sw * v.y;
    } else {
        float4 v = *reinterpret_cast<const float4*>(xs);
        acc[0] = sw * v.x; acc[1] = sw * v.y; acc[2] = sw * v.z; acc[3] = sw * v.w;
    }

    unsigned beg = offs[node], end = offs[node + 1];
    for (unsigned idx = beg; idx < end; ++idx) {
        unsigned s = csr_src[idx];
        float w = csr_w[idx];
        const float* xr = x + (size_t)s * F + lane * VEC;
        if constexpr (VEC == 2) {
            float2 v = *reinterpret_cast<const float2*>(xr);
            acc[0] = fmaf(w, v.x, acc[0]); acc[1] = fmaf(w, v.y, acc[1]);
        } else {
            float4 v = *reinterpret_cast<const float4*>(xr);
            acc[0] = fmaf(w, v.x, acc[0]); acc[1] = fmaf(w, v.y, acc[1]);
            acc[2] = fmaf(w, v.z, acc[2]); acc[3] = fmaf(w, v.w, acc[3]);
        }
    }

    float* yp = y + (size_t)node * F + lane * VEC;
    if constexpr (VEC == 2) {
        *reinterpret_cast<float2*>(yp) = make_float2(acc[0], acc[1]);
    } else {
        *reinterpret_cast<float4*>(yp) = make_float4(acc[0], acc[1], acc[2], acc[3]);
    }
}

// ---------------- GEMM: C = relu(A[M,K] @ B[K,N] + bias) ----------------
// 128x64 tile, 256 threads, 8x4 microtile, BK=16. K%16==0, N%64==0 guaranteed.

__global__ __launch_bounds__(256) void k_gemm_bias_relu(
        const float* __restrict__ A, const float* __restrict__ B,
        const float* __restrict__ bias, float* __restrict__ C,
        int M, int K, int N) {
    __shared__ float As[16][132];  // [k][m], padded: store conflicts <=2-way (free)
    __shared__ float Bs[16][64];

    int tid = (int)threadIdx.x;
    int tr = tid >> 4;        // 0..15 -> 8 rows each
    int tc = tid & 15;        // 0..15 -> 4 cols each
    int brow = blockIdx.y * 128;
    int bcol = blockIdx.x * 64;

    int ar = tid >> 2;        // 0..63 (A load row within tile)
    int ac4 = tid & 3;        // 0..3  (A load float4 index within 16-wide k slab)

    float acc[8][4] = {};

    for (int k0 = 0; k0 < K; k0 += 16) {
        #pragma unroll
        for (int h = 0; h < 2; ++h) {
            int row = brow + ar + h * 64;
            int rowc = row < M ? row : (M - 1);  // clamp (extra rows never stored)
            float4 v = *reinterpret_cast<const float4*>(A + (size_t)rowc * K + k0 + ac4 * 4);
            As[ac4 * 4 + 0][ar + h * 64] = v.x;
            As[ac4 * 4 + 1][ar + h * 64] = v.y;
            As[ac4 * 4 + 2][ar + h * 64] = v.z;
            As[ac4 * 4 + 3][ar + h * 64] = v.w;
        }
        *reinterpret_cast<float4*>(&Bs[tr][tc * 4]) =
            *reinterpret_cast<const float4*>(B + (size_t)(k0 + tr) * N + bcol + tc * 4);
        __syncthreads();

        #pragma unroll
        for (int kk = 0; kk < 16; ++kk) {
            float4 b4 = *reinterpret_cast<const float4*>(&Bs[kk][tc * 4]);
            float4 alo = *reinterpret_cast<const float4*>(&As[kk][tr * 8]);
            float4 ahi = *reinterpret_cast<const float4*>(&As[kk][tr * 8 + 4]);
            float a[8] = {alo.x, alo.y, alo.z, alo.w, ahi.x, ahi.y, ahi.z, ahi.w};
            float b[4] = {b4.x, b4.y, b4.z, b4.w};
            #pragma unroll
            for (int i = 0; i < 8; ++i)
                #pragma unroll
                for (int j = 0; j < 4; ++j)
                    acc[i][j] = fmaf(a[i], b[j], acc[i][j]);
        }
        __syncthreads();
    }

    float4 bv = *reinterpret_cast<const float4*>(&bias[bcol + tc * 4]);
    #pragma unroll
    for (int i = 0; i < 8; ++i) {
        int row = brow + tr * 8 + i;
        if (row < M) {
            float4 o;
            o.x = fmaxf(acc[i][0] + bv.x, 0.f);
            o.y = fmaxf(acc[i][1] + bv.y, 0.f);
            o.z = fmaxf(acc[i][2] + bv.z, 0.f);
            o.w = fmaxf(acc[i][3] + bv.w, 0.f);
            *reinterpret_cast<float4*>(&C[(size_t)row * N + bcol + tc * 4]) = o;
        }
    }
}

// ---------------- launch ----------------

extern "C" void kernel_launch(void* const* d_in, const int* in_sizes, int n_in,
                              void* d_out, int out_size, void* d_ws, size_t ws_size,
                              hipStream_t stream) {
    const float* v  = (const float*)d_in[0];
    const int* ei   = (const int*)d_in[1];   // int32! harness converts integer inputs
    const float* W1 = (const float*)d_in[2];
    const float* b1 = (const float*)d_in[3];
    const float* W2 = (const float*)d_in[4];
    const float* b2 = (const float*)d_in[5];
    const float* W3 = (const float*)d_in[6];
    const float* b3 = (const float*)d_in[7];
    float* out = (float*)d_out;

    char* ws = (char*)d_ws;
    size_t off = 0;
    auto alloc = [&](size_t bytes) {
        void* p = ws + off;
        off = (off + bytes + 255) & ~(size_t)255;
        return p;
    };
    // cnt and cursor adjacent (one memset covers both)
    unsigned* cnt    = (unsigned*)(ws + 0);
    unsigned* cursor = (unsigned*)(ws + (size_t)NN * 4);
    off = ((size_t)NN * 8 + 255) & ~(size_t)255;
    unsigned* offs    = (unsigned*)alloc((size_t)(NN + 1) * 4);
    float*    dinv    = (float*)alloc((size_t)NN * 4);
    float*    selfw   = (float*)alloc((size_t)NN * 4);
    unsigned* csr_src = (unsigned*)alloc((size_t)NE * 4);
    float*    csr_w   = (float*)alloc((size_t)NE * 4);
    float*    bufA    = (float*)alloc((size_t)NN * 256 * 4);  // ws total ~55.4 MB
    // bufB aliases d_out (102.4 MB; bufB needs <=51.2 MB and is fully consumed
    // into bufA before the final GEMM overwrites d_out).
    float*    bufB    = out;

    hipMemsetAsync(cnt, 0, (size_t)NN * 8, stream);  // cnt + cursor

    k_count<<<(NE + 255) / 256, 256, 0, stream>>>(ei, cnt);
    k_dinv<<<(NN + 255) / 256, 256, 0, stream>>>(cnt, dinv, selfw);
    k_scan<<<1, 1024, 0, stream>>>(cnt, offs);
    k_fill<<<(NE + 255) / 256, 256, 0, stream>>>(ei, offs, cursor, dinv, csr_src, csr_w);

    int aggGrid = (NN + 3) / 4;
    int gy = (NN + 127) / 128;

    // Layer 1: y1 = A_hat v ; x1 = relu(y1 @ W1 + b1)   [F=128 -> 128]
    k_aggregate<2><<<aggGrid, 256, 0, stream>>>(v, bufA, offs, csr_src, csr_w, selfw);
    k_gemm_bias_relu<<<dim3(128 / 64, gy), 256, 0, stream>>>(bufA, W1, b1, bufB, NN, 128, 128);

    // Layer 2: y2 = A_hat x1 ; x2 = relu(y2 @ W2 + b2)  [128 -> 256]
    k_aggregate<2><<<aggGrid, 256, 0, stream>>>(bufB, bufA, offs, csr_src, csr_w, selfw);
    k_gemm_bias_relu<<<dim3(256 / 64, gy), 256, 0, stream>>>(bufA, W2, b2, bufB, NN, 128, 256);

    // Layer 3: y3 = A_hat x2 ; out = relu(y3 @ W3 + b3) [256 -> 512]
    k_aggregate<4><<<aggGrid, 256, 0, stream>>>(bufB, bufA, offs, csr_src, csr_w, selfw);
    k_gemm_bias_relu<<<dim3(512 / 64, gy), 256, 0, stream>>>(bufA, W3, b3, out, NN, 256, 512);
}

// Round 3
// 522.540 us; speedup vs baseline: 1.0653x; 1.0653x over previous
//
#include <hip/hip_runtime.h>
#include <hip/hip_bf16.h>
#include <stdint.h>

static constexpr int NN = 50000;   // nodes
static constexpr int NE = 400000;  // edges

typedef __attribute__((ext_vector_type(8))) short bf16x8;
typedef __attribute__((ext_vector_type(4))) float f32x4;

__device__ inline ushort f2bf(float f) {
    __hip_bfloat16 b = __float2bfloat16(f);
    return *reinterpret_cast<ushort*>(&b);
}
__device__ inline float bf2f(ushort u) {
    __hip_bfloat16 b;
    *reinterpret_cast<ushort*>(&b) = u;
    return __bfloat162float(b);
}

// ---------------- CSR build (edge_index is int32 from harness) ----------------

__global__ void k_count(const int* __restrict__ ei, unsigned* __restrict__ cnt) {
    int e = blockIdx.x * blockDim.x + threadIdx.x;
    if (e < NE) atomicAdd(&cnt[ei[NE + e]], 1u);
}

__global__ void k_dinv(const unsigned* __restrict__ cnt, float* __restrict__ dinv) {
    int i = blockIdx.x * blockDim.x + threadIdx.x;
    if (i < NN) dinv[i] = rsqrtf((float)(cnt[i] + 1u));  // deg includes self-loop
}

__global__ __launch_bounds__(1024) void k_scan(const unsigned* __restrict__ cnt,
                                               unsigned* __restrict__ offs) {
    __shared__ unsigned sh[1024];
    __shared__ unsigned carry;
    if (threadIdx.x == 0) carry = 0u;
    __syncthreads();
    for (int base = 0; base < NN; base += 1024) {
        int i = base + (int)threadIdx.x;
        unsigned v = (i < NN) ? cnt[i] : 0u;
        sh[threadIdx.x] = v;
        __syncthreads();
        #pragma unroll
        for (int off = 1; off < 1024; off <<= 1) {
            unsigned add = (threadIdx.x >= (unsigned)off) ? sh[threadIdx.x - off] : 0u;
            __syncthreads();
            sh[threadIdx.x] += add;
            __syncthreads();
        }
        if (i < NN) offs[i] = carry + sh[threadIdx.x] - v;  // exclusive
        __syncthreads();
        if (threadIdx.x == 1023) carry += sh[1023];
        __syncthreads();
    }
    if (threadIdx.x == 0) offs[NN] = carry;
}

__global__ void k_fill(const int* __restrict__ ei, const unsigned* __restrict__ offs,
                       unsigned* __restrict__ cursor, const float* __restrict__ dinv,
                       unsigned* __restrict__ csr_src, float* __restrict__ csr_w) {
    int e = blockIdx.x * blockDim.x + threadIdx.x;
    if (e < NE) {
        int s = ei[e];
        int d = ei[NE + e];
        unsigned pos = offs[d] + atomicAdd(&cursor[d], 1u);
        csr_src[pos] = (unsigned)s;
        csr_w[pos] = dinv[s] * dinv[d];
    }
}

// -------- Weight pre-split: W[K][N] fp32 -> Wt_hi/Wt_lo [N][K] bf16 --------

__global__ void k_splitW(const float* __restrict__ W, ushort* __restrict__ Th,
                         ushort* __restrict__ Tl, int K, int N) {
    int i = blockIdx.x * 256 + (int)threadIdx.x;
    if (i >= K * N) return;
    int k = i / N, n = i - k * N;
    float w = W[i];
    ushort h = f2bf(w);
    ushort l = f2bf(w - bf2f(h));
    Th[n * K + k] = h;
    Tl[n * K + k] = l;
}

// ------- Aggregation: y = A_hat * x, emitted as split bf16 hi/lo -------
// one wave per node; VEC floats/lane; F = 64*VEC

template <int VEC>
__global__ __launch_bounds__(256) void k_aggregate(
        const float* __restrict__ x, ushort* __restrict__ yh, ushort* __restrict__ yl,
        const unsigned* __restrict__ offs, const unsigned* __restrict__ csr_src,
        const float* __restrict__ csr_w, const float* __restrict__ dinv) {
    const int F = 64 * VEC;
    int node = blockIdx.x * 4 + ((int)threadIdx.x >> 6);
    int lane = (int)threadIdx.x & 63;
    if (node >= NN) return;

    float di = dinv[node];
    float sw = di * di;  // self-loop weight
    float acc[VEC];
    const float* xs = x + (size_t)node * F + lane * VEC;
    if constexpr (VEC == 2) {
        float2 v = *reinterpret_cast<const float2*>(xs);
        acc[0] = sw * v.x; acc[1] = sw * v.y;
    } else {
        float4 v = *reinterpret_cast<const float4*>(xs);
        acc[0] = sw * v.x; acc[1] = sw * v.y; acc[2] = sw * v.z; acc[3] = sw * v.w;
    }

    unsigned beg = offs[node], end = offs[node + 1];
    for (unsigned idx = beg; idx < end; ++idx) {
        unsigned s = csr_src[idx];
        float w = csr_w[idx];
        const float* xr = x + (size_t)s * F + lane * VEC;
        if constexpr (VEC == 2) {
            float2 v = *reinterpret_cast<const float2*>(xr);
            acc[0] = fmaf(w, v.x, acc[0]); acc[1] = fmaf(w, v.y, acc[1]);
        } else {
            float4 v = *reinterpret_cast<const float4*>(xr);
            acc[0] = fmaf(w, v.x, acc[0]); acc[1] = fmaf(w, v.y, acc[1]);
            acc[2] = fmaf(w, v.z, acc[2]); acc[3] = fmaf(w, v.w, acc[3]);
        }
    }

    size_t ybase = (size_t)node * F + lane * VEC;
    ushort h[VEC], l[VEC];
    #pragma unroll
    for (int j = 0; j < VEC; ++j) {
        h[j] = f2bf(acc[j]);
        l[j] = f2bf(acc[j] - bf2f(h[j]));
    }
    if constexpr (VEC == 2) {
        *reinterpret_cast<ushort2*>(yh + ybase) = make_ushort2(h[0], h[1]);
        *reinterpret_cast<ushort2*>(yl + ybase) = make_ushort2(l[0], l[1]);
    } else {
        *reinterpret_cast<ushort4*>(yh + ybase) = make_ushort4(h[0], h[1], h[2], h[3]);
        *reinterpret_cast<ushort4*>(yl + ybase) = make_ushort4(l[0], l[1], l[2], l[3]);
    }
}

// ------- GEMM: C = relu(A[M,K] @ W[K,N] + bias) via split-bf16 MFMA -------
// A given as Ah/Al [M][K] bf16; W as Bh/Bl [N][K] bf16 (k-contiguous).
// 3 MFMAs per product: hi*hi + lo*hi + hi*lo (lo*lo dropped, <=2^-18 rel).
// Block: 256 thr = 4 waves (2x2), tile 128x128, wave tile 64x64.
// mfma_f32_16x16x32_bf16: A lane l -> row l&15, k=(l>>4)*8+i ;
// B lane l -> col l&15, same k ; D lane l -> col l&15, row=(l>>4)*4+j.

template <int KT>  // K = KT*32
__global__ __launch_bounds__(256) void k_gemm_mfma(
        const ushort* __restrict__ Ah, const ushort* __restrict__ Al,
        const ushort* __restrict__ Bh, const ushort* __restrict__ Bl,
        const float* __restrict__ bias, float* __restrict__ C,
        int M, int N) {
    const int K = KT * 32;
    int tid = (int)threadIdx.x;
    int w = tid >> 6, lane = tid & 63;
    int wr = w >> 1, wc = w & 1;
    int rbase = blockIdx.y * 128 + wr * 64;
    int cbase = blockIdx.x * 128 + wc * 64;
    int r16 = lane & 15, kg = lane >> 4;

    size_t aoff[4], boff[4];
    #pragma unroll
    for (int mi = 0; mi < 4; ++mi) {
        int row = rbase + mi * 16 + r16;
        if (row >= M) row = M - 1;  // clamp; stores guarded below
        aoff[mi] = (size_t)row * K + kg * 8;
    }
    #pragma unroll
    for (int ni = 0; ni < 4; ++ni) {
        int col = cbase + ni * 16 + r16;
        boff[ni] = (size_t)col * K + kg * 8;
    }

    f32x4 acc[4][4] = {};

    #pragma unroll
    for (int kt = 0; kt < KT; ++kt) {
        bf16x8 ah[4], al[4], bh[4], bl[4];
        #pragma unroll
        for (int mi = 0; mi < 4; ++mi) {
            ah[mi] = *reinterpret_cast<const bf16x8*>(Ah + aoff[mi] + kt * 32);
            al[mi] = *reinterpret_cast<const bf16x8*>(Al + aoff[mi] + kt * 32);
        }
        #pragma unroll
        for (int ni = 0; ni < 4; ++ni) {
            bh[ni] = *reinterpret_cast<const bf16x8*>(Bh + boff[ni] + kt * 32);
            bl[ni] = *reinterpret_cast<const bf16x8*>(Bl + boff[ni] + kt * 32);
        }
        #pragma unroll
        for (int mi = 0; mi < 4; ++mi)
            #pragma unroll
            for (int ni = 0; ni < 4; ++ni) {
                acc[mi][ni] = __builtin_amdgcn_mfma_f32_16x16x32_bf16(ah[mi], bh[ni], acc[mi][ni], 0, 0, 0);
                acc[mi][ni] = __builtin_amdgcn_mfma_f32_16x16x32_bf16(al[mi], bh[ni], acc[mi][ni], 0, 0, 0);
                acc[mi][ni] = __builtin_amdgcn_mfma_f32_16x16x32_bf16(ah[mi], bl[ni], acc[mi][ni], 0, 0, 0);
            }
    }

    int crow0 = (lane >> 4) * 4;
    int ccol = lane & 15;
    #pragma unroll
    for (int ni = 0; ni < 4; ++ni) {
        int col = cbase + ni * 16 + ccol;
        float bv = bias[col];
        #pragma unroll
        for (int mi = 0; mi < 4; ++mi)
            #pragma unroll
            for (int j = 0; j < 4; ++j) {
                int row = rbase + mi * 16 + crow0 + j;
                if (row < M)
                    C[(size_t)row * N + col] = fmaxf(acc[mi][ni][j] + bv, 0.f);
            }
    }
}

// ---------------- launch ----------------

extern "C" void kernel_launch(void* const* d_in, const int* in_sizes, int n_in,
                              void* d_out, int out_size, void* d_ws, size_t ws_size,
                              hipStream_t stream) {
    const float* v  = (const float*)d_in[0];
    const int* ei   = (const int*)d_in[1];
    const float* W1 = (const float*)d_in[2];
    const float* b1 = (const float*)d_in[3];
    const float* W2 = (const float*)d_in[4];
    const float* b2 = (const float*)d_in[5];
    const float* W3 = (const float*)d_in[6];
    const float* b3 = (const float*)d_in[7];
    float* out = (float*)d_out;

    char* ws = (char*)d_ws;
    size_t off = 0;
    auto alloc = [&](size_t bytes) {
        void* p = ws + off;
        off = (off + bytes + 255) & ~(size_t)255;
        return p;
    };
    // cnt+cursor share the front; dead after k_fill -> overlaid by Wt1/Wt2.
    unsigned* cnt    = (unsigned*)(ws + 0);
    unsigned* cursor = (unsigned*)(ws + (size_t)NN * 4);
    ushort* Wt1h = (ushort*)ws;            // 128*128 = 16384 elems
    ushort* Wt1l = Wt1h + 128 * 128;
    ushort* Wt2h = Wt1l + 128 * 128;       // 128*256 = 32768 elems
    ushort* Wt2l = Wt2h + 128 * 256;       // overlay ends at 196,608 B <= 400,000 B
    off = ((size_t)NN * 8 + 255) & ~(size_t)255;
    unsigned* offs    = (unsigned*)alloc((size_t)(NN + 1) * 4);
    float*    dinv    = (float*)alloc((size_t)NN * 4);
    unsigned* csr_src = (unsigned*)alloc((size_t)NE * 4);
    float*    csr_w   = (float*)alloc((size_t)NE * 4);
    // csr_src dead after agg3 -> overlaid by Wt3 (524,288 B <= 1.6 MB).
    ushort* Wt3h = (ushort*)csr_src;       // 256*512 = 131072 elems
    ushort* Wt3l = Wt3h + 256 * 512;
    ushort* aggAh = (ushort*)alloc((size_t)NN * 256 * 2);
    ushort* aggAl = (ushort*)alloc((size_t)NN * 256 * 2);
    // fp32 activations x1/x2 alias d_out (<=51.2 MB, consumed before GEMM3 writes)
    float* bufB = out;

    hipMemsetAsync(cnt, 0, (size_t)NN * 8, stream);  // cnt + cursor

    k_count<<<(NE + 255) / 256, 256, 0, stream>>>(ei, cnt);
    k_dinv<<<(NN + 255) / 256, 256, 0, stream>>>(cnt, dinv);
    k_scan<<<1, 1024, 0, stream>>>(cnt, offs);
    k_fill<<<(NE + 255) / 256, 256, 0, stream>>>(ei, offs, cursor, dinv, csr_src, csr_w);

    // Weight splits (after k_fill: cnt/cursor region is dead)
    k_splitW<<<(128 * 128 + 255) / 256, 256, 0, stream>>>(W1, Wt1h, Wt1l, 128, 128);
    k_splitW<<<(128 * 256 + 255) / 256, 256, 0, stream>>>(W2, Wt2h, Wt2l, 128, 256);

    int aggGrid = (NN + 3) / 4;
    int gy = (NN + 127) / 128;

    // Layer 1: agg(v) -> split bf16 ; MFMA GEMM K=128,N=128 -> x1 (fp32)
    k_aggregate<2><<<aggGrid, 256, 0, stream>>>(v, aggAh, aggAl, offs, csr_src, csr_w, dinv);
    k_gemm_mfma<4><<<dim3(1, gy), 256, 0, stream>>>(aggAh, aggAl, Wt1h, Wt1l, b1, bufB, NN, 128);

    // Layer 2: agg(x1) ; K=128,N=256 -> x2 (fp32)
    k_aggregate<2><<<aggGrid, 256, 0, stream>>>(bufB, aggAh, aggAl, offs, csr_src, csr_w, dinv);
    k_gemm_mfma<4><<<dim3(2, gy), 256, 0, stream>>>(aggAh, aggAl, Wt2h, Wt2l, b2, bufB, NN, 256);

    // Layer 3: agg(x2) ; then Wt3 split (csr_src now dead) ; K=256,N=512 -> out
    k_aggregate<4><<<aggGrid, 256, 0, stream>>>(bufB, aggAh, aggAl, offs, csr_src, csr_w, dinv);
    k_splitW<<<(256 * 512 + 255) / 256, 256, 0, stream>>>(W3, Wt3h, Wt3l, 256, 512);
    k_gemm_mfma<8><<<dim3(4, gy), 256, 0, stream>>>(aggAh, aggAl, Wt3h, Wt3l, b3, out, NN, 512);
}

// Round 4
// 444.789 us; speedup vs baseline: 1.2515x; 1.1748x over previous
//
#include <hip/hip_runtime.h>
#include <hip/hip_bf16.h>
#include <stdint.h>

static constexpr int NN = 50000;   // nodes
static constexpr int NE = 400000;  // edges

typedef __attribute__((ext_vector_type(8))) short bf16x8;
typedef __attribute__((ext_vector_type(4))) float f32x4;

__device__ inline ushort f2bf(float f) {
    __hip_bfloat16 b = __float2bfloat16(f);
    return *reinterpret_cast<ushort*>(&b);
}
__device__ inline float bf2f(ushort u) {
    __hip_bfloat16 b;
    *reinterpret_cast<ushort*>(&b) = u;
    return __bfloat162float(b);
}

__device__ __forceinline__ void gload16(const void* g, void* l) {
    __builtin_amdgcn_global_load_lds(
        (const __attribute__((address_space(1))) void*)g,
        (__attribute__((address_space(3))) void*)l, 16, 0, 0);
}

// ---------------- CSR build (edge_index is int32 from harness) ----------------

__global__ void k_count(const int* __restrict__ ei, unsigned* __restrict__ cnt) {
    int e = blockIdx.x * blockDim.x + threadIdx.x;
    if (e < NE) atomicAdd(&cnt[ei[NE + e]], 1u);
}

__global__ void k_dinv(const unsigned* __restrict__ cnt, float* __restrict__ dinv) {
    int i = blockIdx.x * blockDim.x + threadIdx.x;
    if (i < NN) dinv[i] = rsqrtf((float)(cnt[i] + 1u));  // deg includes self-loop
}

__global__ __launch_bounds__(1024) void k_scan(const unsigned* __restrict__ cnt,
                                               unsigned* __restrict__ offs) {
    __shared__ unsigned sh[1024];
    __shared__ unsigned carry;
    if (threadIdx.x == 0) carry = 0u;
    __syncthreads();
    for (int base = 0; base < NN; base += 1024) {
        int i = base + (int)threadIdx.x;
        unsigned v = (i < NN) ? cnt[i] : 0u;
        sh[threadIdx.x] = v;
        __syncthreads();
        #pragma unroll
        for (int off = 1; off < 1024; off <<= 1) {
            unsigned add = (threadIdx.x >= (unsigned)off) ? sh[threadIdx.x - off] : 0u;
            __syncthreads();
            sh[threadIdx.x] += add;
            __syncthreads();
        }
        if (i < NN) offs[i] = carry + sh[threadIdx.x] - v;  // exclusive
        __syncthreads();
        if (threadIdx.x == 1023) carry += sh[1023];
        __syncthreads();
    }
    if (threadIdx.x == 0) offs[NN] = carry;
}

__global__ void k_fill(const int* __restrict__ ei, const unsigned* __restrict__ offs,
                       unsigned* __restrict__ cursor, const float* __restrict__ dinv,
                       unsigned* __restrict__ csr_src, float* __restrict__ csr_w) {
    int e = blockIdx.x * blockDim.x + threadIdx.x;
    if (e < NE) {
        int s = ei[e];
        int d = ei[NE + e];
        unsigned pos = offs[d] + atomicAdd(&cursor[d], 1u);
        csr_src[pos] = (unsigned)s;
        csr_w[pos] = dinv[s] * dinv[d];
    }
}

// -------- Weight cast+transpose: W[K][N] fp32 -> Wt [N][K] bf16 (hi only) --------

__global__ void k_castW(const float* __restrict__ W, ushort* __restrict__ Wt, int K, int N) {
    int i = blockIdx.x * 256 + (int)threadIdx.x;
    if (i >= K * N) return;
    int k = i / N, n = i - k * N;
    Wt[n * K + k] = f2bf(W[i]);
}

// ------- Aggregation: y = A_hat * x, emitted as split bf16 hi/lo -------

template <int VEC>
__global__ __launch_bounds__(256) void k_aggregate(
        const float* __restrict__ x, ushort* __restrict__ yh, ushort* __restrict__ yl,
        const unsigned* __restrict__ offs, const unsigned* __restrict__ csr_src,
        const float* __restrict__ csr_w, const float* __restrict__ dinv) {
    const int F = 64 * VEC;
    int node = blockIdx.x * 4 + ((int)threadIdx.x >> 6);
    int lane = (int)threadIdx.x & 63;
    if (node >= NN) return;

    float di = dinv[node];
    float sw = di * di;
    float acc[VEC];
    const float* xs = x + (size_t)node * F + lane * VEC;
    if constexpr (VEC == 2) {
        float2 v = *reinterpret_cast<const float2*>(xs);
        acc[0] = sw * v.x; acc[1] = sw * v.y;
    } else {
        float4 v = *reinterpret_cast<const float4*>(xs);
        acc[0] = sw * v.x; acc[1] = sw * v.y; acc[2] = sw * v.z; acc[3] = sw * v.w;
    }

    unsigned beg = offs[node], end = offs[node + 1];
    for (unsigned idx = beg; idx < end; ++idx) {
        unsigned s = csr_src[idx];
        float w = csr_w[idx];
        const float* xr = x + (size_t)s * F + lane * VEC;
        if constexpr (VEC == 2) {
            float2 v = *reinterpret_cast<const float2*>(xr);
            acc[0] = fmaf(w, v.x, acc[0]); acc[1] = fmaf(w, v.y, acc[1]);
        } else {
            float4 v = *reinterpret_cast<const float4*>(xr);
            acc[0] = fmaf(w, v.x, acc[0]); acc[1] = fmaf(w, v.y, acc[1]);
            acc[2] = fmaf(w, v.z, acc[2]); acc[3] = fmaf(w, v.w, acc[3]);
        }
    }

    size_t ybase = (size_t)node * F + lane * VEC;
    ushort h[VEC], l[VEC];
    #pragma unroll
    for (int j = 0; j < VEC; ++j) {
        h[j] = f2bf(acc[j]);
        l[j] = f2bf(acc[j] - bf2f(h[j]));
    }
    if constexpr (VEC == 2) {
        *reinterpret_cast<ushort2*>(yh + ybase) = make_ushort2(h[0], h[1]);
        *reinterpret_cast<ushort2*>(yl + ybase) = make_ushort2(l[0], l[1]);
    } else {
        *reinterpret_cast<ushort4*>(yh + ybase) = make_ushort4(h[0], h[1], h[2], h[3]);
        *reinterpret_cast<ushort4*>(yl + ybase) = make_ushort4(l[0], l[1], l[2], l[3]);
    }
}

// ------- GEMM: C = relu(A[M,K] @ W[K,N] + bias), LDS-staged 2-phase pipeline -------
// A as Ah/Al [M][K] bf16; W as Wt [N][K] bf16 (k-contiguous).
// 2 MFMAs per product: ah*b + al*b (weight stays single bf16).
// Tile 128x128, BK=32, 4 waves (2x2, 64x64 each), 2x double-buffered LDS.
// LDS tile layout kg-major: chunk(kg,row) 16B at [(kg*128+row)*16] -> fragment
// ds_read_b128 by 16 consecutive rows = consecutive 16B slots (conflict-free).

template <int NT, int GX>  // K = NT*32 ; GX = N/128
__global__ __launch_bounds__(256, 3) void k_gemm2(
        const ushort* __restrict__ Ah, const ushort* __restrict__ Al,
        const ushort* __restrict__ Wt, const float* __restrict__ bias,
        float* __restrict__ C, int M, int N) {
    constexpr int K = NT * 32;
    __shared__ __align__(16) short smem[2][3 * 4096];  // per buf: Ah | Al | B (8KB each)

    // bijective XCD swizzle (m204): each XCD gets a contiguous swz range
    int nwg = (int)gridDim.x;
    int bid = (int)blockIdx.x;
    int q = nwg >> 3, r = nwg & 7;
    int xcd = bid & 7, seq = bid >> 3;
    int swz = (xcd < r ? xcd * (q + 1) : r * (q + 1) + (xcd - r) * q) + seq;
    int bx = swz % GX, by = swz / GX;

    int tid = (int)threadIdx.x;
    int w = tid >> 6, lane = tid & 63;
    int wr = w >> 1, wc = w & 1;
    int r16 = lane & 15, kg = lane >> 4;
    int row0 = by * 128, col0 = bx * 128;

    // staging: 512 chunks per 8KB tile; thread covers chunks c0 = w*64+lane and c0+256.
    // chunk c -> kg = c>>7, row = c&127. For c0: kg = wr; for c1: kg = wr+2.
    int c0 = w * 64 + lane;
    int cs = c0 & 127;                       // row within tile (same for both issues)
    int rowA = row0 + cs; if (rowA >= M) rowA = M - 1;   // clamp; never stored
    const ushort* sA0h = Ah + (size_t)rowA * K + wr * 8;
    const ushort* sA1h = Ah + (size_t)rowA * K + (wr + 2) * 8;
    const ushort* sA0l = Al + (size_t)rowA * K + wr * 8;
    const ushort* sA1l = Al + (size_t)rowA * K + (wr + 2) * 8;
    const ushort* sB0  = Wt + (size_t)(col0 + cs) * K + wr * 8;
    const ushort* sB1  = Wt + (size_t)(col0 + cs) * K + (wr + 2) * 8;
    int d0 = c0 * 8, d1 = (c0 + 256) * 8;    // LDS short offsets within a tile

    auto stage = [&](int b, int t) {
        short* sb = &smem[b][0];
        int ko = t * 32;
        gload16(sA0h + ko, sb + d0);
        gload16(sA1h + ko, sb + d1);
        gload16(sA0l + ko, sb + 4096 + d0);
        gload16(sA1l + ko, sb + 4096 + d1);
        gload16(sB0 + ko, sb + 8192 + d0);
        gload16(sB1 + ko, sb + 8192 + d1);
    };

    f32x4 acc[4][4] = {};
    int aoff = (kg * 128 + wr * 64 + r16) * 8;
    int boff = 8192 + (kg * 128 + wc * 64 + r16) * 8;

    stage(0, 0);
    __syncthreads();

    for (int t = 0; t < NT; ++t) {
        int cur = t & 1;
        if (t + 1 < NT) stage(cur ^ 1, t + 1);

        const short* sb = &smem[cur][0];
        bf16x8 a_h[4], a_l[4], bb[4];
        #pragma unroll
        for (int mi = 0; mi < 4; ++mi) {
            a_h[mi] = *reinterpret_cast<const bf16x8*>(sb + aoff + mi * 128);
            a_l[mi] = *reinterpret_cast<const bf16x8*>(sb + 4096 + aoff + mi * 128);
        }
        #pragma unroll
        for (int ni = 0; ni < 4; ++ni)
            bb[ni] = *reinterpret_cast<const bf16x8*>(sb + boff + ni * 128);

        #pragma unroll
        for (int mi = 0; mi < 4; ++mi)
            #pragma unroll
            for (int ni = 0; ni < 4; ++ni) {
                acc[mi][ni] = __builtin_amdgcn_mfma_f32_16x16x32_bf16(a_h[mi], bb[ni], acc[mi][ni], 0, 0, 0);
                acc[mi][ni] = __builtin_amdgcn_mfma_f32_16x16x32_bf16(a_l[mi], bb[ni], acc[mi][ni], 0, 0, 0);
            }

        if (t + 1 < NT) __syncthreads();  // drains gload_lds (vmcnt) + readers of cur
    }

    // epilogue: D lane l -> col = l&15, row = (l>>4)*4 + j
    int crow0 = (lane >> 4) * 4;
    int ccol = lane & 15;
    int rb = row0 + wr * 64;
    int cb = col0 + wc * 64;
    #pragma unroll
    for (int ni = 0; ni < 4; ++ni) {
        int col = cb + ni * 16 + ccol;
        float bv = bias[col];
        #pragma unroll
        for (int mi = 0; mi < 4; ++mi)
            #pragma unroll
            for (int j = 0; j < 4; ++j) {
                int row = rb + mi * 16 + crow0 + j;
                if (row < M)
                    C[(size_t)row * N + col] = fmaxf(acc[mi][ni][j] + bv, 0.f);
            }
    }
}

// ---------------- launch ----------------

extern "C" void kernel_launch(void* const* d_in, const int* in_sizes, int n_in,
                              void* d_out, int out_size, void* d_ws, size_t ws_size,
                              hipStream_t stream) {
    const float* v  = (const float*)d_in[0];
    const int* ei   = (const int*)d_in[1];
    const float* W1 = (const float*)d_in[2];
    const float* b1 = (const float*)d_in[3];
    const float* W2 = (const float*)d_in[4];
    const float* b2 = (const float*)d_in[5];
    const float* W3 = (const float*)d_in[6];
    const float* b3 = (const float*)d_in[7];
    float* out = (float*)d_out;

    char* ws = (char*)d_ws;
    size_t off = 0;
    auto alloc = [&](size_t bytes) {
        void* p = ws + off;
        off = (off + bytes + 255) & ~(size_t)255;
        return p;
    };
    // cnt+cursor at front; dead after k_fill -> overlaid by Wt1/Wt2 (96KB <= 400KB).
    unsigned* cnt    = (unsigned*)(ws + 0);
    unsigned* cursor = (unsigned*)(ws + (size_t)NN * 4);
    ushort* Wt1 = (ushort*)ws;               // [128][128] = 32KB
    ushort* Wt2 = Wt1 + 128 * 128;           // [256][128] = 64KB
    off = ((size_t)NN * 8 + 255) & ~(size_t)255;
    unsigned* offs    = (unsigned*)alloc((size_t)(NN + 1) * 4);
    float*    dinv    = (float*)alloc((size_t)NN * 4);
    unsigned* csr_src = (unsigned*)alloc((size_t)NE * 4);
    float*    csr_w   = (float*)alloc((size_t)NE * 4);
    // csr_src dead after agg3 -> overlaid by Wt3 [512][256] = 256KB <= 1.6MB.
    ushort* Wt3 = (ushort*)csr_src;
    ushort* aggAh = (ushort*)alloc((size_t)NN * 256 * 2);
    ushort* aggAl = (ushort*)alloc((size_t)NN * 256 * 2);
    float* bufB = out;  // fp32 activations alias d_out (consumed before final GEMM writes)

    hipMemsetAsync(cnt, 0, (size_t)NN * 8, stream);  // cnt + cursor

    k_count<<<(NE + 255) / 256, 256, 0, stream>>>(ei, cnt);
    k_dinv<<<(NN + 255) / 256, 256, 0, stream>>>(cnt, dinv);
    k_scan<<<1, 1024, 0, stream>>>(cnt, offs);
    k_fill<<<(NE + 255) / 256, 256, 0, stream>>>(ei, offs, cursor, dinv, csr_src, csr_w);

    // Weight casts (after k_fill: cnt/cursor region is dead)
    k_castW<<<(128 * 128 + 255) / 256, 256, 0, stream>>>(W1, Wt1, 128, 128);
    k_castW<<<(128 * 256 + 255) / 256, 256, 0, stream>>>(W2, Wt2, 128, 256);

    int aggGrid = (NN + 3) / 4;
    int gy = (NN + 127) / 128;  // 391

    // Layer 1: agg(v) -> split bf16 ; GEMM K=128,N=128 -> x1 (fp32)
    k_aggregate<2><<<aggGrid, 256, 0, stream>>>(v, aggAh, aggAl, offs, csr_src, csr_w, dinv);
    k_gemm2<4, 1><<<gy * 1, 256, 0, stream>>>(aggAh, aggAl, Wt1, b1, bufB, NN, 128);

    // Layer 2: agg(x1) ; GEMM K=128,N=256 -> x2 (fp32)
    k_aggregate<2><<<aggGrid, 256, 0, stream>>>(bufB, aggAh, aggAl, offs, csr_src, csr_w, dinv);
    k_gemm2<4, 2><<<gy * 2, 256, 0, stream>>>(aggAh, aggAl, Wt2, b2, bufB, NN, 256);

    // Layer 3: agg(x2) ; cast W3 (csr_src now dead) ; GEMM K=256,N=512 -> out
    k_aggregate<4><<<aggGrid, 256, 0, stream>>>(bufB, aggAh, aggAl, offs, csr_src, csr_w, dinv);
    k_castW<<<(256 * 512 + 255) / 256, 256, 0, stream>>>(W3, Wt3, 256, 512);
    k_gemm2<8, 4><<<gy * 4, 256, 0, stream>>>(aggAh, aggAl, Wt3, b3, out, NN, 512);
}

// Round 5
// 365.233 us; speedup vs baseline: 1.5242x; 1.2178x over previous
//
#include <hip/hip_runtime.h>
#include <hip/hip_bf16.h>
#include <stdint.h>

static constexpr int NN = 50000;   // nodes
static constexpr int NE = 400000;  // edges
static constexpr int NB = (NN + 1023) / 1024;  // 49 scan blocks

typedef __attribute__((ext_vector_type(8))) short bf16x8;
typedef __attribute__((ext_vector_type(4))) float f32x4;

__device__ inline ushort f2bf(float f) {
    __hip_bfloat16 b = __float2bfloat16(f);
    return *reinterpret_cast<ushort*>(&b);
}
__device__ inline float bf2f(ushort u) {
    __hip_bfloat16 b;
    *reinterpret_cast<ushort*>(&b) = u;
    return __bfloat162float(b);
}

__device__ __forceinline__ void gload16(const void* g, void* l) {
    __builtin_amdgcn_global_load_lds(
        (const __attribute__((address_space(1))) void*)g,
        (__attribute__((address_space(3))) void*)l, 16, 0, 0);
}

// ---------------- CSR build (edge_index is int32 from harness) ----------------

__global__ void k_count(const int* __restrict__ ei, unsigned* __restrict__ cnt) {
    int e = blockIdx.x * blockDim.x + threadIdx.x;
    if (e < NE) atomicAdd(&cnt[ei[NE + e]], 1u);
}

__global__ void k_dinv(const unsigned* __restrict__ cnt, float* __restrict__ dinv) {
    int i = blockIdx.x * blockDim.x + threadIdx.x;
    if (i < NN) dinv[i] = rsqrtf((float)(cnt[i] + 1u));  // deg includes self-loop
}

// --- hierarchical exclusive scan: 49 parallel blocks -> top scan -> add ---

__global__ __launch_bounds__(1024) void k_scan1(const unsigned* __restrict__ cnt,
                                                unsigned* __restrict__ offs,
                                                unsigned* __restrict__ bsum) {
    __shared__ unsigned sh[1024];
    int i = blockIdx.x * 1024 + (int)threadIdx.x;
    unsigned v = (i < NN) ? cnt[i] : 0u;
    sh[threadIdx.x] = v;
    __syncthreads();
    #pragma unroll
    for (int off = 1; off < 1024; off <<= 1) {
        unsigned add = (threadIdx.x >= (unsigned)off) ? sh[threadIdx.x - off] : 0u;
        __syncthreads();
        sh[threadIdx.x] += add;
        __syncthreads();
    }
    if (i < NN) offs[i] = sh[threadIdx.x] - v;  // block-local exclusive
    if (threadIdx.x == 1023) bsum[blockIdx.x] = sh[1023];
}

__global__ void k_scan2(const unsigned* __restrict__ bsum, unsigned* __restrict__ boff,
                        unsigned* __restrict__ offs) {
    if (threadIdx.x == 0) {
        unsigned acc = 0;
        for (int b = 0; b < NB; ++b) { boff[b] = acc; acc += bsum[b]; }
        offs[NN] = acc;  // == NE
    }
}

__global__ __launch_bounds__(1024) void k_scan3(unsigned* __restrict__ offs,
                                                const unsigned* __restrict__ boff) {
    int i = blockIdx.x * 1024 + (int)threadIdx.x;
    if (i < NN) offs[i] += boff[blockIdx.x];
}

__global__ void k_fill(const int* __restrict__ ei, const unsigned* __restrict__ offs,
                       unsigned* __restrict__ cursor, const float* __restrict__ dinv,
                       unsigned* __restrict__ csr_src, float* __restrict__ csr_w) {
    int e = blockIdx.x * blockDim.x + threadIdx.x;
    if (e < NE) {
        int s = ei[e];
        int d = ei[NE + e];
        unsigned pos = offs[d] + atomicAdd(&cursor[d], 1u);
        csr_src[pos] = (unsigned)s;
        csr_w[pos] = dinv[s] * dinv[d];
    }
}

// -------- Weight cast+transpose: W[K][N] fp32 -> Wt [N][K] bf16 (hi only) --------

__global__ void k_castW(const float* __restrict__ W, ushort* __restrict__ Wt, int K, int N) {
    int i = blockIdx.x * 256 + (int)threadIdx.x;
    if (i >= K * N) return;
    int k = i / N, n = i - k * N;
    Wt[n * K + k] = f2bf(W[i]);
}

// ------- Aggregation: y = A_hat * x, emitted as split bf16 hi/lo -------

template <int VEC>
__global__ __launch_bounds__(256) void k_aggregate(
        const float* __restrict__ x, ushort* __restrict__ yh, ushort* __restrict__ yl,
        const unsigned* __restrict__ offs, const unsigned* __restrict__ csr_src,
        const float* __restrict__ csr_w, const float* __restrict__ dinv) {
    const int F = 64 * VEC;
    int node = blockIdx.x * 4 + ((int)threadIdx.x >> 6);
    int lane = (int)threadIdx.x & 63;
    if (node >= NN) return;

    float di = dinv[node];
    float sw = di * di;
    float acc[VEC];
    const float* xs = x + (size_t)node * F + lane * VEC;
    if constexpr (VEC == 2) {
        float2 v = *reinterpret_cast<const float2*>(xs);
        acc[0] = sw * v.x; acc[1] = sw * v.y;
    } else {
        float4 v = *reinterpret_cast<const float4*>(xs);
        acc[0] = sw * v.x; acc[1] = sw * v.y; acc[2] = sw * v.z; acc[3] = sw * v.w;
    }

    unsigned beg = offs[node], end = offs[node + 1];
    for (unsigned idx = beg; idx < end; ++idx) {
        unsigned s = csr_src[idx];
        float w = csr_w[idx];
        const float* xr = x + (size_t)s * F + lane * VEC;
        if constexpr (VEC == 2) {
            float2 v = *reinterpret_cast<const float2*>(xr);
            acc[0] = fmaf(w, v.x, acc[0]); acc[1] = fmaf(w, v.y, acc[1]);
        } else {
            float4 v = *reinterpret_cast<const float4*>(xr);
            acc[0] = fmaf(w, v.x, acc[0]); acc[1] = fmaf(w, v.y, acc[1]);
            acc[2] = fmaf(w, v.z, acc[2]); acc[3] = fmaf(w, v.w, acc[3]);
        }
    }

    size_t ybase = (size_t)node * F + lane * VEC;
    ushort h[VEC], l[VEC];
    #pragma unroll
    for (int j = 0; j < VEC; ++j) {
        h[j] = f2bf(acc[j]);
        l[j] = f2bf(acc[j] - bf2f(h[j]));
    }
    if constexpr (VEC == 2) {
        *reinterpret_cast<ushort2*>(yh + ybase) = make_ushort2(h[0], h[1]);
        *reinterpret_cast<ushort2*>(yl + ybase) = make_ushort2(l[0], l[1]);
    } else {
        *reinterpret_cast<ushort4*>(yh + ybase) = make_ushort4(h[0], h[1], h[2], h[3]);
        *reinterpret_cast<ushort4*>(yl + ybase) = make_ushort4(l[0], l[1], l[2], l[3]);
    }
}

// ------- GEMM: C = relu(A[M,K] @ W[K,N] + bias), LDS-staged 2-phase pipeline -------
// (structure validated R4: tile 128x128, BK=32, 4 waves 2x2, double-buffered LDS,
//  global_load_lds width=16, kg-major LDS layout, bijective XCD swizzle)

template <int NT, int GX>  // K = NT*32 ; GX = N/128
__global__ __launch_bounds__(256, 3) void k_gemm2(
        const ushort* __restrict__ Ah, const ushort* __restrict__ Al,
        const ushort* __restrict__ Wt, const float* __restrict__ bias,
        float* __restrict__ C, int M, int N) {
    constexpr int K = NT * 32;
    __shared__ __align__(16) short smem[2][3 * 4096];  // per buf: Ah | Al | B

    int nwg = (int)gridDim.x;
    int bid = (int)blockIdx.x;
    int q = nwg >> 3, r = nwg & 7;
    int xcd = bid & 7, seq = bid >> 3;
    int swz = (xcd < r ? xcd * (q + 1) : r * (q + 1) + (xcd - r) * q) + seq;
    int bx = swz % GX, by = swz / GX;

    int tid = (int)threadIdx.x;
    int w = tid >> 6, lane = tid & 63;
    int wr = w >> 1, wc = w & 1;
    int r16 = lane & 15, kg = lane >> 4;
    int row0 = by * 128, col0 = bx * 128;

    int c0 = w * 64 + lane;
    int cs = c0 & 127;
    int rowA = row0 + cs; if (rowA >= M) rowA = M - 1;   // clamp; never stored
    const ushort* sA0h = Ah + (size_t)rowA * K + wr * 8;
    const ushort* sA1h = Ah + (size_t)rowA * K + (wr + 2) * 8;
    const ushort* sA0l = Al + (size_t)rowA * K + wr * 8;
    const ushort* sA1l = Al + (size_t)rowA * K + (wr + 2) * 8;
    const ushort* sB0  = Wt + (size_t)(col0 + cs) * K + wr * 8;
    const ushort* sB1  = Wt + (size_t)(col0 + cs) * K + (wr + 2) * 8;
    int d0 = c0 * 8, d1 = (c0 + 256) * 8;

    auto stage = [&](int b, int t) {
        short* sb = &smem[b][0];
        int ko = t * 32;
        gload16(sA0h + ko, sb + d0);
        gload16(sA1h + ko, sb + d1);
        gload16(sA0l + ko, sb + 4096 + d0);
        gload16(sA1l + ko, sb + 4096 + d1);
        gload16(sB0 + ko, sb + 8192 + d0);
        gload16(sB1 + ko, sb + 8192 + d1);
    };

    f32x4 acc[4][4] = {};
    int aoff = (kg * 128 + wr * 64 + r16) * 8;
    int boff = 8192 + (kg * 128 + wc * 64 + r16) * 8;

    stage(0, 0);
    __syncthreads();

    for (int t = 0; t < NT; ++t) {
        int cur = t & 1;
        if (t + 1 < NT) stage(cur ^ 1, t + 1);

        const short* sb = &smem[cur][0];
        bf16x8 a_h[4], a_l[4], bb[4];
        #pragma unroll
        for (int mi = 0; mi < 4; ++mi) {
            a_h[mi] = *reinterpret_cast<const bf16x8*>(sb + aoff + mi * 128);
            a_l[mi] = *reinterpret_cast<const bf16x8*>(sb + 4096 + aoff + mi * 128);
        }
        #pragma unroll
        for (int ni = 0; ni < 4; ++ni)
            bb[ni] = *reinterpret_cast<const bf16x8*>(sb + boff + ni * 128);

        #pragma unroll
        for (int mi = 0; mi < 4; ++mi)
            #pragma unroll
            for (int ni = 0; ni < 4; ++ni) {
                acc[mi][ni] = __builtin_amdgcn_mfma_f32_16x16x32_bf16(a_h[mi], bb[ni], acc[mi][ni], 0, 0, 0);
                acc[mi][ni] = __builtin_amdgcn_mfma_f32_16x16x32_bf16(a_l[mi], bb[ni], acc[mi][ni], 0, 0, 0);
            }

        if (t + 1 < NT) __syncthreads();
    }

    int crow0 = (lane >> 4) * 4;
    int ccol = lane & 15;
    int rb = row0 + wr * 64;
    int cb = col0 + wc * 64;
    #pragma unroll
    for (int ni = 0; ni < 4; ++ni) {
        int col = cb + ni * 16 + ccol;
        float bv = bias[col];
        #pragma unroll
        for (int mi = 0; mi < 4; ++mi)
            #pragma unroll
            for (int j = 0; j < 4; ++j) {
                int row = rb + mi * 16 + crow0 + j;
                if (row < M)
                    C[(size_t)row * N + col] = fmaxf(acc[mi][ni][j] + bv, 0.f);
            }
    }
}

// ---------------- launch ----------------

extern "C" void kernel_launch(void* const* d_in, const int* in_sizes, int n_in,
                              void* d_out, int out_size, void* d_ws, size_t ws_size,
                              hipStream_t stream) {
    const float* v  = (const float*)d_in[0];
    const int* ei   = (const int*)d_in[1];
    const float* W1 = (const float*)d_in[2];
    const float* b1 = (const float*)d_in[3];
    const float* W2 = (const float*)d_in[4];
    const float* b2 = (const float*)d_in[5];
    const float* W3 = (const float*)d_in[6];
    const float* b3 = (const float*)d_in[7];
    float* out = (float*)d_out;

    char* ws = (char*)d_ws;
    size_t off = 0;
    auto alloc = [&](size_t bytes) {
        void* p = ws + off;
        off = (off + bytes + 255) & ~(size_t)255;
        return p;
    };
    // cnt+cursor at front; dead after k_fill -> overlaid by Wt1/Wt2 (96KB <= 400KB).
    unsigned* cnt    = (unsigned*)(ws + 0);
    unsigned* cursor = (unsigned*)(ws + (size_t)NN * 4);
    ushort* Wt1 = (ushort*)ws;               // [128][128] = 32KB
    ushort* Wt2 = Wt1 + 128 * 128;           // [256][128] = 64KB
    off = ((size_t)NN * 8 + 255) & ~(size_t)255;
    unsigned* offs    = (unsigned*)alloc((size_t)(NN + 1) * 4);
    float*    dinv    = (float*)alloc((size_t)NN * 4);
    unsigned* bsum    = (unsigned*)alloc((size_t)NB * 4);
    unsigned* boff    = (unsigned*)alloc((size_t)NB * 4);
    unsigned* csr_src = (unsigned*)alloc((size_t)NE * 4);
    float*    csr_w   = (float*)alloc((size_t)NE * 4);
    // csr_src dead after agg3 -> overlaid by Wt3 [512][256] = 256KB <= 1.6MB.
    ushort* Wt3 = (ushort*)csr_src;
    ushort* aggAh = (ushort*)alloc((size_t)NN * 256 * 2);
    ushort* aggAl = (ushort*)alloc((size_t)NN * 256 * 2);
    float* bufB = out;  // fp32 activations alias d_out (consumed before final GEMM writes)

    hipMemsetAsync(cnt, 0, (size_t)NN * 8, stream);  // cnt + cursor

    k_count<<<(NE + 255) / 256, 256, 0, stream>>>(ei, cnt);
    k_dinv<<<(NN + 255) / 256, 256, 0, stream>>>(cnt, dinv);
    k_scan1<<<NB, 1024, 0, stream>>>(cnt, offs, bsum);
    k_scan2<<<1, 64, 0, stream>>>(bsum, boff, offs);
    k_scan3<<<NB, 1024, 0, stream>>>(offs, boff);
    k_fill<<<(NE + 255) / 256, 256, 0, stream>>>(ei, offs, cursor, dinv, csr_src, csr_w);

    // Weight casts (after k_fill: cnt/cursor region is dead)
    k_castW<<<(128 * 128 + 255) / 256, 256, 0, stream>>>(W1, Wt1, 128, 128);
    k_castW<<<(128 * 256 + 255) / 256, 256, 0, stream>>>(W2, Wt2, 128, 256);

    int aggGrid = (NN + 3) / 4;
    int gy = (NN + 127) / 128;  // 391

    // Layer 1: agg(v) -> split bf16 ; GEMM K=128,N=128 -> x1 (fp32)
    k_aggregate<2><<<aggGrid, 256, 0, stream>>>(v, aggAh, aggAl, offs, csr_src, csr_w, dinv);
    k_gemm2<4, 1><<<gy * 1, 256, 0, stream>>>(aggAh, aggAl, Wt1, b1, bufB, NN, 128);

    // Layer 2: agg(x1) ; GEMM K=128,N=256 -> x2 (fp32)
    k_aggregate<2><<<aggGrid, 256, 0, stream>>>(bufB, aggAh, aggAl, offs, csr_src, csr_w, dinv);
    k_gemm2<4, 2><<<gy * 2, 256, 0, stream>>>(aggAh, aggAl, Wt2, b2, bufB, NN, 256);

    // Layer 3: agg(x2) ; cast W3 (csr_src now dead) ; GEMM K=256,N=512 -> out
    k_aggregate<4><<<aggGrid, 256, 0, stream>>>(bufB, aggAh, aggAl, offs, csr_src, csr_w, dinv);
    k_castW<<<(256 * 512 + 255) / 256, 256, 0, stream>>>(W3, Wt3, 256, 512);
    k_gemm2<8, 4><<<gy * 4, 256, 0, stream>>>(aggAh, aggAl, Wt3, b3, out, NN, 512);
}